// Round 5
// baseline (584.187 us; speedup 1.0000x reference)
//
#include <hip/hip_runtime.h>
#include <hip/hip_fp16.h>

typedef unsigned short u16;
typedef unsigned int   u32;
typedef __attribute__((ext_vector_type(8))) short short8;
typedef __attribute__((ext_vector_type(4))) float f32x4;

#define NN 256
#define DD 128

__device__ __forceinline__ u16 f2b(float f) {
    union { float f; u32 i; } v; v.f = f;
    u32 x = v.i;
    return (u16)((x + 0x7FFFu + ((x >> 16) & 1u)) >> 16);  // RTN-even
}
__device__ __forceinline__ float b2f(u16 u) {
    union { u32 i; float f; } v; v.i = ((u32)u) << 16; return v.f;
}
// HW packed f32->bf16 (RNE), 1 instr for 2 values: lo in [15:0], hi in [31:16]
__device__ __forceinline__ u32 cvtpk(float lo, float hi) {
    u32 r;
    asm("v_cvt_pk_bf16_f32 %0, %1, %2" : "=v"(r) : "v"(lo), "v"(hi));
    return r;
}
__device__ __forceinline__ float sigm(float z) { return 1.f / (1.f + __expf(-z)); }

// ---------------------------------------------------------------------------
// Kernel 1: repack 6 f32 weight matrices [d][h] into bf16 MFMA B-fragment
// order: frag[(mat*8+nt)*4+s][lane][8] where lane=(quad<<4)|m holds
// w[d = s*32+quad*8 .. +8][h = nt*16+m].
// order: 0=w_left 1=w_lgate 2=w_right 3=w_rgate 4=w_ogate 5=w_out
// ---------------------------------------------------------------------------
__global__ void k_tw(const float* w0, const float* w1, const float* w2,
                     const float* w3, const float* w4, const float* w5,
                     u16* __restrict__ out) {
    int t = blockIdx.x * 256 + threadIdx.x;   // 12288 threads, 8 outputs each
    int mat = t >> 11, idx = t & 2047;        // idx = (nt*4+s)*64 + lane
    int lane = idx & 63;
    int s    = (idx >> 6) & 3;
    int nt   = idx >> 8;
    int m = lane & 15, quad = lane >> 4;
    int h  = nt * 16 + m;
    int d0 = s * 32 + quad * 8;
    const float* src = (mat == 0) ? w0 : (mat == 1) ? w1 : (mat == 2) ? w2
                      : (mat == 3) ? w3 : (mat == 4) ? w4 : w5;
    u16 vals[8];
#pragma unroll
    for (int j = 0; j < 8; ++j) vals[j] = f2b(src[(d0 + j) * 128 + h]);
    *(uint4*)(out + (t << 3)) = *(uint4*)vals;   // t*8 = mat*16384 + idx*8
}

// ---------------------------------------------------------------------------
// Kernel 2: LayerNorm + 5 GEMMs + gating.
// Block = (b, q, ptile): 128 rows (b, p0..p0+127, q).
// LN loads: 32 lanes/row x contiguous float4 (2-seg instrs).
// lT/rT (MFMA-fragment order) and og are ALL staged in LDS and bulk-stored
// in two h-halves: fragment-order bulk store = 8 x 64B segs/instr (was
// 16 x 32B scattered directly from acc).  LDS 50 KiB -> still 3 blocks/CU.
// ---------------------------------------------------------------------------
__global__ __launch_bounds__(256, 4)
void k_lngemm(const float* __restrict__ x,
              const float* __restrict__ ng,  const float* __restrict__ nb,
              const u16*   __restrict__ wT,
              const float* __restrict__ bL,  const float* __restrict__ bLG,
              const float* __restrict__ bR,  const float* __restrict__ bRG,
              const float* __restrict__ bOG,
              u16* __restrict__ lT, u16* __restrict__ rT, u16* __restrict__ ogu)
{
    // 51200 B union:
    //  phase 1: xs = xn bf16 tile, uint4[128*16] (32 KiB)
    //  phase 2 (per h-half): lS u16[64][132], rS u16[64][132], ogS f16[128][68]
    __shared__ uint4 smemU[3200];
    uint4* xs = smemU;
    u16*   lS  = (u16*)smemU;            // [h' 64][p 128 +4pad]
    u16*   rS  = lS + 64 * 132;
    __half* ogS = (__half*)(lS + 2 * 64 * 132);   // [p 128][h' 64 +4pad]

    const int tid = threadIdx.x;
    const int bx  = blockIdx.x;
    const int b   = bx >> 9;
    const int q   = (bx >> 1) & 255;
    const int p0  = (bx & 1) * 128;

    // ---- LN phase: 32 lanes per row (contiguous 512B), 8 rows per pass ----
    {
        const int rr = tid >> 5;   // row-within-pass 0..7
        const int c  = tid & 31;   // float4 chunk 0..31
        float4 gv = *(const float4*)(ng + c * 4);
        float4 bv = *(const float4*)(nb + c * 4);
#pragma unroll
        for (int pass = 0; pass < 16; ++pass) {
            const int r = pass * 8 + rr;                  // local row 0..127
            const long gRow = (long)((b * NN + p0 + r) * NN + q);
            float4 xv = *(const float4*)(x + gRow * DD + c * 4);
            float s1 = xv.x + xv.y + xv.z + xv.w;
            float s2 = xv.x*xv.x + xv.y*xv.y + xv.z*xv.z + xv.w*xv.w;
#pragma unroll
            for (int off = 1; off < 32; off <<= 1) {
                s1 += __shfl_xor(s1, off);
                s2 += __shfl_xor(s2, off);
            }
            const float mu = s1 * (1.f / 128.f);
            const float rs = rsqrtf(s2 * (1.f / 128.f) - mu * mu + 1e-5f);
            uint2 pk;
            pk.x = cvtpk((xv.x-mu)*rs*gv.x+bv.x, (xv.y-mu)*rs*gv.y+bv.y);
            pk.y = cvtpk((xv.z-mu)*rs*gv.z+bv.z, (xv.w-mu)*rs*gv.w+bv.w);
            // 16B chunk ch = c>>1 (half c&1), xor-swizzled like before
            ((uint2*)xs)[(r * 16 + ((c >> 1) ^ (r & 15))) * 2 + (c & 1)] = pk;
        }
    }
    __syncthreads();

    // ---- GEMM phase: wave w owns rows w*32..w*32+31 (2 m-tiles) ----
    const int w = tid >> 6, lane = tid & 63, quad = lane >> 4, m = lane & 15;

    short8 af[2][4];
#pragma unroll
    for (int mt = 0; mt < 2; ++mt)
#pragma unroll
        for (int s = 0; s < 4; ++s) {
            const int row = w * 32 + mt * 16 + m;
            af[mt][s] = *(const short8*)(xs + row * 16 + ((s * 4 + quad) ^ m));
        }
    __syncthreads();   // xs consumed by all waves -> safe to reuse as lS/rS/ogS

    const int qt = q >> 4, qm = q & 15, pc0 = p0 >> 5;

#pragma unroll 1
    for (int half = 0; half < 2; ++half) {
#pragma unroll 2
        for (int ntl = 0; ntl < 4; ++ntl) {
            const int nt = half * 4 + ntl;
            const int h  = nt * 16 + m;
            const int hh = ntl * 16 + m;    // h' within half
            f32x4 acc[5][2];
            const f32x4 zero = {0.f, 0.f, 0.f, 0.f};
#pragma unroll
            for (int g5 = 0; g5 < 5; ++g5) { acc[g5][0] = zero; acc[g5][1] = zero; }

#pragma unroll
            for (int g5 = 0; g5 < 5; ++g5) {
                // fragment-ordered weights: coalesced lane*16B loads
                const u16* wfb = wT + ((((g5 << 3) + nt) << 2) << 9) + (lane << 3);
#pragma unroll
                for (int s = 0; s < 4; ++s) {
                    short8 bf = *(const short8*)(wfb + (s << 9));
                    acc[g5][0] = __builtin_amdgcn_mfma_f32_16x16x32_bf16(af[0][s], bf, acc[g5][0], 0, 0, 0);
                    acc[g5][1] = __builtin_amdgcn_mfma_f32_16x16x32_bf16(af[1][s], bf, acc[g5][1], 0, 0, 0);
                }
            }
            const float vbl  = bL[h],  vblg = bLG[h];
            const float vbr  = bR[h],  vbrg = bRG[h];
            const float vbog = bOG[h];
#pragma unroll
            for (int mt = 0; mt < 2; ++mt) {
                const int pl = w * 32 + mt * 16 + quad * 4;   // local p base
                float lvf[4], rvf[4];
#pragma unroll
                for (int rg = 0; rg < 4; ++rg) {
                    lvf[rg] = (acc[0][mt][rg] + vbl) * sigm(acc[1][mt][rg] + vblg);
                    rvf[rg] = (acc[2][mt][rg] + vbr) * sigm(acc[3][mt][rg] + vbrg);
                    float ov = sigm(acc[4][mt][rg] + vbog);
                    ogS[(pl + rg) * 68 + hh] = __float2half(ov);
                }
                uint2 lp2, rp2;
                lp2.x = cvtpk(lvf[0], lvf[1]); lp2.y = cvtpk(lvf[2], lvf[3]);
                rp2.x = cvtpk(rvf[0], rvf[1]); rp2.y = cvtpk(rvf[2], rvf[3]);
                *(uint2*)(lS + hh * 132 + pl) = lp2;
                *(uint2*)(rS + hh * 132 + pl) = rp2;
            }
        }
        __syncthreads();

        // ---- bulk store this h-half ----
        // lT/rT: fragment order, 64B contiguous per (h,pc): 8 segs/instr
        {
#pragma unroll
            for (int pass = 0; pass < 8; ++pass) {
                const int sid = pass * 32 + (tid >> 3);   // 0..255
                const int hh  = sid >> 2;                 // 0..63
                const int pcl = sid & 3;                  // local p-chunk
                const int e   = (tid & 7) * 4;            // elem within chunk
                const int h   = half * 64 + hh;
                const long off = ((((long)(b * 128 + h) * 16 + qt) * 8 + pc0 + pcl) << 9)
                               + qm * 32 + e;
                *(uint2*)(lT + off) = *(const uint2*)(lS + hh * 132 + pcl * 32 + e);
                *(uint2*)(rT + off) = *(const uint2*)(rS + hh * 132 + pcl * 32 + e);
            }
        }
        // og: 128B contiguous per p-row (4 segs/instr)
        {
#pragma unroll
            for (int pass = 0; pass < 8; ++pass) {
                const int p = pass * 16 + (tid >> 4);
                const int c = tid & 15;
                uint2 o = *(const uint2*)((const u16*)ogS + p * 68 + c * 4);
                const long row = (long)((b * NN + p0 + p) * NN + q);
                *(uint2*)(ogu + row * 256 + half * 64 + c * 4) = o;
            }
        }
        if (half == 0) __syncthreads();
    }
}

// ---------------------------------------------------------------------------
// Kernel 3: mix.  Per (b,d): C[i,j] = sum_k right[k,i]*left[k,j].  lT/rT in
// MFMA-fragment order -> dense 1KB fragment loads.  Output staged in LDS
// (XOR-swizzled) and bulk-stored as 256B row runs.
// ---------------------------------------------------------------------------
__global__ __launch_bounds__(256)
void k_mix(const u16* __restrict__ lT, const u16* __restrict__ rT,
           u16* __restrict__ mx)
{
    __shared__ u16 Cs[128 * 128];   // 32 KiB C-tile
    const int tid = threadIdx.x;
    const int bx  = blockIdx.x;
    const int bd  = bx >> 2;               // b*128 + d
    const int it  = (bx >> 1) & 1, jt = bx & 1;
    const int w = tid >> 6, lane = tid & 63, quad = lane >> 4, m = lane & 15;
    const int iwl = (w >> 1) * 64;           // wave tile origin within Cs
    const int jwl = (w & 1) * 64;
    const int iqt = it * 8 + (w >> 1) * 4;   // base i-tile (qt) index
    const int jqt = jt * 8 + (w & 1) * 4;    // base j-tile (qt) index
    const int fo = m * 32 + quad * 8;        // lane offset within fragment

    f32x4 acc[4][4];
    const f32x4 zero = {0.f, 0.f, 0.f, 0.f};
#pragma unroll
    for (int a = 0; a < 4; ++a)
#pragma unroll
        for (int c = 0; c < 4; ++c) acc[a][c] = zero;

#pragma unroll 1
    for (int kc = 0; kc < 8; ++kc) {
        short8 afr[4], bfr[4];
#pragma unroll
        for (int tI = 0; tI < 4; ++tI)
            afr[tI] = *(const short8*)(rT + (((long)(bd * 16 + iqt + tI) << 3) + kc) * 512 + fo);
#pragma unroll
        for (int tJ = 0; tJ < 4; ++tJ)
            bfr[tJ] = *(const short8*)(lT + (((long)(bd * 16 + jqt + tJ) << 3) + kc) * 512 + fo);
#pragma unroll
        for (int tI = 0; tI < 4; ++tI)
#pragma unroll
            for (int tJ = 0; tJ < 4; ++tJ)
                acc[tI][tJ] = __builtin_amdgcn_mfma_f32_16x16x32_bf16(bfr[tJ], afr[tI], acc[tI][tJ], 0, 0, 0);
    }

    // D transposed: col = i = m, row = j = quad*4+rg -> uint2 into LDS
#pragma unroll
    for (int tI = 0; tI < 4; ++tI)
#pragma unroll
        for (int tJ = 0; tJ < 4; ++tJ) {
            const int iL = iwl + tI * 16 + m;
            const int jL = jwl + tJ * 16 + quad * 4;
            uint2 vv;
            vv.x = cvtpk(acc[tI][tJ][0], acc[tI][tJ][1]);
            vv.y = cvtpk(acc[tI][tJ][2], acc[tI][tJ][3]);
            *(uint2*)(Cs + iL * 128 + (jL ^ ((iL & 7) << 3))) = vv;
        }
    __syncthreads();

    // bulk store: 128 rows x 256B contiguous (2-seg instrs)
    {
        const int ir = tid >> 5, cc = tid & 31;
        const int ib0 = it * 128, jb0 = jt * 128;
#pragma unroll
        for (int pass = 0; pass < 16; ++pass) {
            const int iL = pass * 8 + ir;
            uint2 v = *(const uint2*)(Cs + iL * 128 + ((cc * 4) ^ ((iL & 7) << 3)));
            *(uint2*)(mx + (long)bd * 65536 + (ib0 + iL) * 256 + jb0 + cc * 4) = v;
        }
    }
}

// ---------------------------------------------------------------------------
// Kernel 4: final.  Block = (b, i, j-tile of 64).  Loads mx[b,:,i,j0:j0+64],
// LN over d per j, * ogate (f16, packed in d_out row slots — each block reads
// only its own rows before overwriting them), then y @ w_outT + b_out.
// og prefetched to registers (2-seg row loads).  Output via LDS bulk store.
// ---------------------------------------------------------------------------
__global__ __launch_bounds__(256)
void k_final(const u16* __restrict__ mx, const u16* __restrict__ ogu,
             const u16* __restrict__ wT5, const float* __restrict__ ong,
             const float* __restrict__ onb, const float* __restrict__ bo_,
             float* __restrict__ out)
{
    // layout: [0,18432)   m1  : uint4 [128][9]  (8 data + 1 pad) bf16
    //         [18432,34816) ys: uint4 [64][16]  bf16 A-frag layout
    //         [34816,35072) mu_s, [35072,35328) rs_s
    //         outs f32 [64 j][128 e] = [0,32768)  -- reuses m1+ys after barrier
    __shared__ __align__(16) unsigned char smem[35328];
    uint4* m1   = (uint4*)smem;
    uint4* ys   = (uint4*)(smem + 18432);
    float* mu_s = (float*)(smem + 34816);
    float* rs_s = (float*)(smem + 35072);
    float* outs = (float*)smem;

    const int tid = threadIdx.x;
    const int bx  = blockIdx.x;
    const int b   = bx >> 10;
    const int i   = (bx >> 2) & 255;
    const int j0  = (bx & 3) * 64;
    const long base = ((long)b * 128) * 65536 + (long)i * 256 + j0;

    // ---- og prefetch: 8 x uint2, row-contiguous (2-seg instrs) ----
    uint2 ogp[8];
    {
        const int rr = tid >> 5, c = tid & 31;
#pragma unroll
        for (int pass = 0; pass < 8; ++pass) {
            const long r = (long)((b * NN + i) * NN + j0 + pass * 8 + rr);
            ogp[pass] = *(const uint2*)(ogu + r * 256 + c * 4);
        }
    }

    {   // load mixed tile: 128 d-rows x 64 j (bf16)
        const int dr = tid >> 3, cc = tid & 7;
#pragma unroll
        for (int pass = 0; pass < 4; ++pass) {
            const int d = pass * 32 + dr;
            m1[d * 9 + cc] = *(const uint4*)(mx + base + (long)d * 65536 + cc * 8);
        }
    }
    __syncthreads();

    if (tid < 128) {   // stats: 2 threads per j
        const int j = tid >> 1, half = tid & 1;
        float s1 = 0.f, s2 = 0.f;
        for (int d = half * 64; d < half * 64 + 64; ++d) {
            float v = b2f(((const u16*)(m1 + d * 9))[j]);
            s1 += v; s2 += v * v;
        }
        s1 += __shfl_xor(s1, 1); s2 += __shfl_xor(s2, 1);
        if (half == 0) {
            const float mu = s1 * (1.f / 128.f);
            mu_s[j] = mu;
            rs_s[j] = rsqrtf(s2 * (1.f / 128.f) - mu * mu + 1e-5f);
        }
    }
    __syncthreads();

    {   // y = (LN(mixed) * ogate) staged bf16 in A-frag layout
        const int rr = tid >> 5, c = tid & 31;
        float4 gv4 = *(const float4*)(ong + c * 4);
        float4 bv4 = *(const float4*)(onb + c * 4);
        const float gvv[4] = {gv4.x, gv4.y, gv4.z, gv4.w};
        const float bvv[4] = {bv4.x, bv4.y, bv4.z, bv4.w};
#pragma unroll
        for (int pass = 0; pass < 8; ++pass) {
            const int j = pass * 8 + rr;
            const float mu = mu_s[j], rs = rs_s[j];
            const __half* oh = (const __half*)&ogp[pass];
            float yv[4];
#pragma unroll
            for (int k = 0; k < 4; ++k) {
                const int d = c * 4 + k;
                const float v = b2f(((const u16*)m1)[d * 72 + j]);
                yv[k] = ((v - mu) * rs * gvv[k] + bvv[k]) * __half2float(oh[k]);
            }
            uint2 pk;
            pk.x = cvtpk(yv[0], yv[1]);
            pk.y = cvtpk(yv[2], yv[3]);
            ((uint2*)ys)[(j * 16 + ((c >> 1) ^ (j & 15))) * 2 + (c & 1)] = pk;
        }
    }
    __syncthreads();

    // GEMM: 64 j-rows x 128 e, K = 128.  wave w -> m-tile w.
    const int w = tid >> 6, lane = tid & 63, quad = lane >> 4, m = lane & 15;
    short8 afr[4];
#pragma unroll
    for (int s = 0; s < 4; ++s)
        afr[s] = *(const short8*)(ys + (w * 16 + m) * 16 + ((s * 4 + quad) ^ m));
    __syncthreads();   // ys consumed -> safe to reuse LDS as outs

#pragma unroll 1
    for (int et = 0; et < 8; ++et) {
        f32x4 acc = {0.f, 0.f, 0.f, 0.f};
#pragma unroll
        for (int s = 0; s < 4; ++s) {
            // fragment-ordered w_out: coalesced lane*16B loads
            short8 bfr = *(const short8*)(wT5 + (((et << 2) + s) << 9) + (lane << 3));
            acc = __builtin_amdgcn_mfma_f32_16x16x32_bf16(afr[s], bfr, acc, 0, 0, 0);
        }
        const int e = et * 16 + m;
        const float bo = bo_[e];
#pragma unroll
        for (int rg = 0; rg < 4; ++rg) {
            const int jl = w * 16 + quad * 4 + rg;
            outs[jl * 128 + e] = acc[rg] + bo;
        }
    }
    __syncthreads();

    {   // bulk store: 64 rows x 512B, fully contiguous 32 KiB per block
#pragma unroll
        for (int it2 = 0; it2 < 8; ++it2) {
            const int jl = it2 * 8 + w * 2 + (lane >> 5);
            const int e4 = (lane & 31) * 4;
            float4 o = *(const float4*)(outs + jl * 128 + e4);
            *(float4*)(out + ((long)((b * NN + i) * NN + j0 + jl)) * DD + e4) = o;
        }
    }
}

// ---------------------------------------------------------------------------
extern "C" void kernel_launch(void* const* d_in, const int* in_sizes, int n_in,
                              void* d_out, int out_size, void* d_ws, size_t ws_size,
                              hipStream_t stream) {
    const float* x   = (const float*)d_in[0];
    const float* ng  = (const float*)d_in[1];
    const float* nb  = (const float*)d_in[2];
    const float* wl  = (const float*)d_in[3];
    const float* bl  = (const float*)d_in[4];
    const float* wr  = (const float*)d_in[5];
    const float* br  = (const float*)d_in[6];
    const float* wlg = (const float*)d_in[7];
    const float* blg = (const float*)d_in[8];
    const float* wrg = (const float*)d_in[9];
    const float* brg = (const float*)d_in[10];
    const float* wog = (const float*)d_in[11];
    const float* bog = (const float*)d_in[12];
    const float* ong = (const float*)d_in[13];
    const float* onb = (const float*)d_in[14];
    const float* wo  = (const float*)d_in[15];
    const float* bo  = (const float*)d_in[16];

    u16* ws = (u16*)d_ws;
    const long BIG = 33554432;          // 4*128*256*256 elements
    // Workspace: lT, rT, mx (bf16, 3 x 64 MiB) + 192 KiB bf16 weights.
    // og (f16) aliases d_out: packed in the first 256B of each 512B out-row
    // slot; k_final reads only its own rows before overwriting them.
    const size_t need = (size_t)(3 * BIG + 6 * 16384) * sizeof(u16);
    if (ws_size < need) return;  // clean failure instead of OOB fault

    u16* lT = ws;                        // bf16, fragment order (see k_lngemm)
    u16* rT = lT + BIG;                  // bf16, fragment order
    u16* mx = rT + BIG;                  // bf16 [b,d,i,j]
    u16* wT = mx + BIG;                  // bf16, 6 mats in MFMA fragment order
    u16* og = (u16*)d_out;               // f16, row-slot packed (aliases d_out)

    k_tw<<<48, 256, 0, stream>>>(wl, wlg, wr, wrg, wog, wo, wT);
    k_lngemm<<<2048, 256, 0, stream>>>(x, ng, nb, wT, bl, blg, br, brg, bog, lT, rT, og);
    k_mix<<<2048, 256, 0, stream>>>(lT, rT, mx);
    k_final<<<4096, 256, 0, stream>>>(mx, og, wT + 5 * 16384, ong, onb, bo, (float*)d_out);
}